// Round 11
// baseline (490.464 us; speedup 1.0000x reference)
//
#include <hip/hip_runtime.h>

// ---------------------------------------------------------------------------
// GraphSAGE 2-layer hetero (R=2) + edge dot scorer.  Round 11:
//  * PHYSICALLY SLICED gather tables: xb [4][N][32], t0/t1 [2][N][32],
//    h2 [2][N][32] (bf16). Slice = contiguous 3.2 MB region -> fits one XCD
//    4 MB L2 with no 128-B line sharing across slices. blockIdx&mask pins
//    slice->XCD (round-robin heuristic; neutral if mapping differs).
//  * agg gathers: 16 lanes/edge x 4 edges per wave-instruction (64-B
//    coalesced segments), shfl_xor(16/32) cross-group reduce. Same
//    instruction count per edge as round 10, all requests XCD-L2-local.
//  * score: per-slice partial dots + f32 atomicAdd into zeroed out.
//  * MFMA gemm3/gemm2, CSR bucket build, prep unchanged in spirit; gemm A
//    reads adapted to sliced layouts.
// ---------------------------------------------------------------------------

#define BW 128            // nodes per radix bucket (pow2)
#define NBK_MAX 1024
#define EPB 8192          // edges per block in radix passes

typedef __attribute__((ext_vector_type(8))) short bf16x8;
typedef __attribute__((ext_vector_type(4))) float floatx4;

__device__ __forceinline__ unsigned short f2bf(float f) {
    unsigned u = __float_as_uint(f);
    unsigned r = u + 0x7FFFu + ((u >> 16) & 1u);
    return (unsigned short)(r >> 16);
}
__device__ __forceinline__ unsigned pack2(float a, float b) {
    return (unsigned)f2bf(a) | ((unsigned)f2bf(b) << 16);
}
__device__ __forceinline__ float bflo(unsigned v) { return __uint_as_float(v << 16); }
__device__ __forceinline__ float bfhi(unsigned v) { return __uint_as_float(v & 0xFFFF0000u); }

// ---- radix pass A: per-(r,bucket) counts --------------------------------
__global__ __launch_bounds__(256) void
bucket_count_kernel(const int* __restrict__ edges, int* __restrict__ bcnt,
                    int NBK, int E)
{
    __shared__ int cnt[2 * NBK_MAX];
    const int rbT = 2 * NBK;
    const int t = threadIdx.x;
    for (int k = t; k < rbT; k += 256) cnt[k] = 0;
    __syncthreads();
    long long start = (long long)blockIdx.x * EPB;
    long long twoE = 2LL * E;
    for (int u = 0; u < EPB / 256; ++u) {
        long long idx = start + u * 256 + t;
        if (idx < twoE) {
            int r = idx >= E;
            int e = (int)(idx - (long long)r * E);
            int d = edges[(size_t)r * 2 * E + E + e];
            atomicAdd(&cnt[r * NBK + (d >> 7)], 1);
        }
    }
    __syncthreads();
    for (int k = t; k < rbT; k += 256)
        if (cnt[k]) atomicAdd(&bcnt[k], cnt[k]);
}

// ---- radix pass B: exclusive scan of bucket counts ----------------------
__global__ __launch_bounds__(1024) void
bucket_scan_kernel(const int* __restrict__ bcnt, int* __restrict__ bko,
                   int rbT, int twoE)
{
    __shared__ int sm[1024];
    int t = threadIdx.x;
    int v = (t < rbT) ? bcnt[t] : 0;
    sm[t] = v;
    __syncthreads();
    for (int s = 1; s < 1024; s <<= 1) {
        int u = (t >= s) ? sm[t - s] : 0;
        __syncthreads();
        sm[t] += u;
        __syncthreads();
    }
    if (t < rbT) bko[t] = sm[t] - v;
    if (t == 0) bko[rbT] = twoE;
}

// ---- radix pass C: partition into packed (src | dstLocal<<24) -----------
__global__ __launch_bounds__(256) void
partition_kernel(const int* __restrict__ edges, const int* __restrict__ bko,
                 int* __restrict__ gcur, unsigned* __restrict__ staging,
                 int NBK, int E)
{
    __shared__ int cnt[2 * NBK_MAX];
    __shared__ int base[2 * NBK_MAX];
    const int rbT = 2 * NBK;
    const int t = threadIdx.x;
    for (int k = t; k < rbT; k += 256) cnt[k] = 0;
    __syncthreads();
    long long start = (long long)blockIdx.x * EPB;
    long long twoE = 2LL * E;
    for (int u = 0; u < EPB / 256; ++u) {
        long long idx = start + u * 256 + t;
        if (idx < twoE) {
            int r = idx >= E;
            int e = (int)(idx - (long long)r * E);
            int d = edges[(size_t)r * 2 * E + E + e];
            atomicAdd(&cnt[r * NBK + (d >> 7)], 1);
        }
    }
    __syncthreads();
    for (int k = t; k < rbT; k += 256) {
        int c0 = cnt[k];
        if (c0) base[k] = bko[k] + atomicAdd(&gcur[k], c0);
        cnt[k] = 0;
    }
    __syncthreads();
    for (int u = 0; u < EPB / 256; ++u) {
        long long idx = start + u * 256 + t;
        if (idx < twoE) {
            int r = idx >= E;
            int e = (int)(idx - (long long)r * E);
            int s = edges[(size_t)r * 2 * E + e];
            int d = edges[(size_t)r * 2 * E + E + e];
            int rb = r * NBK + (d >> 7);
            int pos = atomicAdd(&cnt[rb], 1);
            staging[(size_t)base[rb] + pos] = (unsigned)s | ((unsigned)(d & 127) << 24);
        }
    }
}

// ---- radix pass D: per-bucket node hist/scan -> off[] and csr[] ----------
__global__ __launch_bounds__(256) void
bucket_csr_kernel(const unsigned* __restrict__ staging, const int* __restrict__ bko,
                  int* __restrict__ csr, int* __restrict__ off,
                  int NBK, int N)
{
    __shared__ int hist[BW], excl[BW], cur[BW], sc[BW];
    const int rb = blockIdx.x;
    const int r = rb / NBK;
    const int b = rb % NBK;
    const int node0 = b * BW;
    const int nn = min(BW, N - node0);
    const int cbase = bko[rb];
    const int c = bko[rb + 1] - cbase;
    const int t = threadIdx.x;

    if (t < BW) { hist[t] = 0; cur[t] = 0; }
    __syncthreads();
    for (int k = t; k < c; k += 256)
        atomicAdd(&hist[staging[(size_t)cbase + k] >> 24], 1);
    __syncthreads();
    if (t < BW) sc[t] = hist[t];
    __syncthreads();
    for (int s = 1; s < BW; s <<= 1) {
        int v = (t < BW && t >= s) ? sc[t - s] : 0;
        __syncthreads();
        if (t < BW) sc[t] += v;
        __syncthreads();
    }
    if (t < BW) excl[t] = sc[t] - hist[t];
    if (t < nn) off[(size_t)r * N + node0 + t] = cbase + excl[t];
    __syncthreads();
    for (int k = t; k < c; k += 256) {
        unsigned pr = staging[(size_t)cbase + k];
        int l = (int)(pr >> 24);
        int pos = atomicAdd(&cur[l], 1);
        csr[(size_t)cbase + excl[l] + pos] = (int)(pr & 0xFFFFFFu);
    }
}

// ---- f32 [N,128] -> bf16 sliced [4][N][32] ------------------------------
__global__ __launch_bounds__(256) void
cvt_sliced_kernel(const float* __restrict__ x, unsigned short* __restrict__ xs, int N)
{
    int t = blockIdx.x * blockDim.x + threadIdx.x;
    if (t >= N * 16) return;
    int n = t >> 4;
    int q = t & 15;
    int slice = q >> 2;
    int chunk = q & 3;
    const float* ip = x + (size_t)n * 128 + slice * 32 + chunk * 8;
    float4 v0 = *(const float4*)ip;
    float4 v1 = *(const float4*)(ip + 4);
    uint4 o;
    o.x = pack2(v0.x, v0.y); o.y = pack2(v0.z, v0.w);
    o.z = pack2(v1.x, v1.y); o.w = pack2(v1.z, v1.w);
    *(uint4*)(xs + ((size_t)slice * N + n) * 32 + chunk * 8) = o;
}

// ---- weight prep: combined-Wself / Wn -> bf16 W^T rows, biases ----------
__global__ void prep_kernel(const float* __restrict__ Ws1, const float* __restrict__ Wn1,
                            const float* __restrict__ b1,
                            const float* __restrict__ Ws2, const float* __restrict__ Wn2,
                            const float* __restrict__ b2,
                            unsigned short* __restrict__ WT1z, unsigned short* __restrict__ WT1a,
                            unsigned short* __restrict__ WT1b, float* __restrict__ bc1,
                            unsigned short* __restrict__ WT2z, unsigned short* __restrict__ WT2a,
                            unsigned short* __restrict__ WT2b, float* __restrict__ bc2)
{
    int t = blockIdx.x * blockDim.x + threadIdx.x;
    if (t < 16384) {                 // layer 1: [n][k] <- [k][n]
        int n = t >> 7, k = t & 127;
        int in = k * 128 + n;
        WT1z[t] = f2bf(Ws1[in] + Ws1[16384 + in]);
        WT1a[t] = f2bf(Wn1[in]);
        WT1b[t] = f2bf(Wn1[16384 + in]);
    }
    if (t < 8192) {                  // layer 2: n < 64, k < 128
        int n = t >> 7, k = t & 127;
        int in = k * 64 + n;
        WT2z[t] = f2bf(Ws2[in] + Ws2[8192 + in]);
        WT2a[t] = f2bf(Wn2[in]);
        WT2b[t] = f2bf(Wn2[8192 + in]);
    }
    if (t < 128) bc1[t] = b1[t] + b1[128 + t];
    if (t < 64)  bc2[t] = b2[t] + b2[64 + t];
}

// ---- agg1x sliced: slice=blockIdx&3, wave per (r,node), 4 edges/instr ----
// xb sliced [4][N][32]; outputs m0/m1 sliced [4][N][32].
__global__ __launch_bounds__(256) void
agg1x_kernel(const unsigned short* __restrict__ xs,
             const int* __restrict__ csr, const int* __restrict__ off,
             unsigned short* __restrict__ m0s, unsigned short* __restrict__ m1s,
             int N, int twoE)
{
    const int slice = blockIdx.x & 3;
    int w = (blockIdx.x >> 2) * 4 + (threadIdx.x >> 6);
    int lane = threadIdx.x & 63;
    if (w >= 2 * N) return;
    const int eg = lane >> 4;        // 0..3 edge within batch
    const int c2 = (lane & 15) * 2;  // col within slice
    const unsigned short* tb = xs + (size_t)slice * N * 32;
    unsigned short* outp = ((w < N) ? m0s : m1s) + (size_t)slice * N * 32;
    int node = (w < N) ? w : w - N;

    int o0 = off[w];
    int o1 = (w + 1 < 2 * N) ? off[w + 1] : twoE;
    int d = o1 - o0;

    float sx = 0.f, sy = 0.f;
    int j = o0;
    for (; j + 15 < o1; j += 16) {
        unsigned a[4];
#pragma unroll
        for (int q = 0; q < 4; ++q)
            a[q] = *(const unsigned*)(tb + (size_t)csr[j + q * 4 + eg] * 32 + c2);
#pragma unroll
        for (int q = 0; q < 4; ++q) { sx += bflo(a[q]); sy += bfhi(a[q]); }
    }
    for (; j < o1; j += 4) {
        int jj = j + eg;
        if (jj < o1) {
            unsigned a = *(const unsigned*)(tb + (size_t)csr[jj] * 32 + c2);
            sx += bflo(a); sy += bfhi(a);
        }
    }
    sx += __shfl_xor(sx, 16);
    sx += __shfl_xor(sx, 32);
    sy += __shfl_xor(sy, 16);
    sy += __shfl_xor(sy, 32);
    if (eg == 0) {
        float inv = 1.0f / fmaxf((float)d, 1.0f);
        *(unsigned*)(outp + (size_t)node * 32 + c2) = pack2(sx * inv, sy * inv);
    }
}

// ---- gemm3 (layer 1): h1 = relu(xb@W0 + m0@W1 + m1@W2 + bias) -> bf16 ---
// A inputs sliced [4][N][32]; h1b row-major [N,128].
__global__ __launch_bounds__(256) void
gemm3_mfma_kernel(const unsigned short* __restrict__ xs,
                  const unsigned short* __restrict__ m0s,
                  const unsigned short* __restrict__ m1s,
                  const unsigned short* __restrict__ WT0,
                  const unsigned short* __restrict__ WT1,
                  const unsigned short* __restrict__ WT2,
                  const float* __restrict__ bias,
                  unsigned short* __restrict__ h1b, int N)
{
    __shared__ float eb[64][129];
    const int tid = threadIdx.x;
    const int wave = tid >> 6;
    const int lane = tid & 63;
    const int m = lane & 15;
    const int quad = lane >> 4;

    floatx4 acc[8];
    const floatx4 z4 = {0.f, 0.f, 0.f, 0.f};
#pragma unroll
    for (int t = 0; t < 8; ++t) acc[t] = z4;

    int arow = blockIdx.x * 64 + wave * 16 + m;
    if (arow >= N) arow = N - 1;

    const unsigned short* Asrc[3] = {xs, m0s, m1s};
    const unsigned short* Bsrc[3] = {WT0, WT1, WT2};
#pragma unroll
    for (int s3 = 0; s3 < 3; ++s3) {
        const unsigned short* ab = Asrc[s3];
        const unsigned short* bp = Bsrc[s3];
#pragma unroll
        for (int s = 0; s < 4; ++s) {       // K-chunk s == slice s
            bf16x8 a = *(const bf16x8*)(ab + ((size_t)s * N + arow) * 32 + quad * 8);
#pragma unroll
            for (int t = 0; t < 8; ++t) {
                bf16x8 b = *(const bf16x8*)(bp + (size_t)(t * 16 + m) * 128 + s * 32 + quad * 8);
                acc[t] = __builtin_amdgcn_mfma_f32_16x16x32_bf16(a, b, acc[t], 0, 0, 0);
            }
        }
    }

#pragma unroll
    for (int t = 0; t < 8; ++t)
#pragma unroll
        for (int i = 0; i < 4; ++i)
            eb[wave * 16 + quad * 4 + i][t * 16 + m] = acc[t][i];
    __syncthreads();

#pragma unroll
    for (int j = 0; j < 4; ++j) {
        int lr = wave * 16 + j * 4 + quad;
        int grow = blockIdx.x * 64 + lr;
        if (grow < N) {
#pragma unroll
            for (int i = 0; i < 2; ++i) {
                int c0 = (i * 16 + m) * 4;
                float v0 = fmaxf(eb[lr][c0 + 0] + bias[c0 + 0], 0.0f);
                float v1 = fmaxf(eb[lr][c0 + 1] + bias[c0 + 1], 0.0f);
                float v2 = fmaxf(eb[lr][c0 + 2] + bias[c0 + 2], 0.0f);
                float v3 = fmaxf(eb[lr][c0 + 3] + bias[c0 + 3], 0.0f);
                ushort4 u;
                u.x = f2bf(v0); u.y = f2bf(v1); u.z = f2bf(v2); u.w = f2bf(v3);
                *(ushort4*)(h1b + (size_t)grow * 128 + c0) = u;
            }
        }
    }
}

// ---- gemm2 (layer 2): one A pass -> z2b row-major, t0/t1 sliced [2][N][32]
__global__ __launch_bounds__(256) void
gemm2_mfma_kernel(const unsigned short* __restrict__ h1b,
                  const unsigned short* __restrict__ WTz,
                  const unsigned short* __restrict__ WTa,
                  const unsigned short* __restrict__ WTb,
                  const float* __restrict__ bias,
                  unsigned short* __restrict__ z2b,
                  unsigned short* __restrict__ t0s, unsigned short* __restrict__ t1s,
                  int N)
{
    __shared__ float eb[64][65];
    const int tid = threadIdx.x;
    const int wave = tid >> 6;
    const int lane = tid & 63;
    const int m = lane & 15;
    const int quad = lane >> 4;

    floatx4 acc[3][4];
    const floatx4 z4 = {0.f, 0.f, 0.f, 0.f};
#pragma unroll
    for (int o = 0; o < 3; ++o)
#pragma unroll
        for (int t = 0; t < 4; ++t) acc[o][t] = z4;

    int arow = blockIdx.x * 64 + wave * 16 + m;
    if (arow >= N) arow = N - 1;
    const unsigned short* ap = h1b + (size_t)arow * 128 + quad * 8;
    const unsigned short* Bsrc[3] = {WTz, WTa, WTb};

#pragma unroll
    for (int s = 0; s < 4; ++s) {
        bf16x8 a = *(const bf16x8*)(ap + s * 32);
#pragma unroll
        for (int o = 0; o < 3; ++o)
#pragma unroll
            for (int t = 0; t < 4; ++t) {
                bf16x8 b = *(const bf16x8*)(Bsrc[o] + (size_t)(t * 16 + m) * 128 + s * 32 + quad * 8);
                acc[o][t] = __builtin_amdgcn_mfma_f32_16x16x32_bf16(a, b, acc[o][t], 0, 0, 0);
            }
    }

#pragma unroll
    for (int o = 0; o < 3; ++o) {
#pragma unroll
        for (int t = 0; t < 4; ++t)
#pragma unroll
            for (int i = 0; i < 4; ++i)
                eb[wave * 16 + quad * 4 + i][t * 16 + m] = acc[o][t][i];
        __syncthreads();
#pragma unroll
        for (int j = 0; j < 4; ++j) {
            int lr = wave * 16 + j * 4 + quad;
            int grow = blockIdx.x * 64 + lr;
            if (grow < N) {
                int c0 = m * 4;
                float v0 = eb[lr][c0 + 0], v1 = eb[lr][c0 + 1];
                float v2 = eb[lr][c0 + 2], v3 = eb[lr][c0 + 3];
                ushort4 u;
                if (o == 0) {
                    v0 += bias[c0 + 0]; v1 += bias[c0 + 1];
                    v2 += bias[c0 + 2]; v3 += bias[c0 + 3];
                    u.x = f2bf(v0); u.y = f2bf(v1); u.z = f2bf(v2); u.w = f2bf(v3);
                    *(ushort4*)(z2b + (size_t)grow * 64 + c0) = u;
                } else {
                    u.x = f2bf(v0); u.y = f2bf(v1); u.z = f2bf(v2); u.w = f2bf(v3);
                    unsigned short* tp = (o == 1) ? t0s : t1s;
                    int slice = m >> 3;
                    int scol = c0 & 31;
                    *(ushort4*)(tp + ((size_t)slice * N + grow) * 32 + scol) = u;
                }
            }
        }
        __syncthreads();
    }
}

// ---- agg2 sliced: combo=blockIdx&3 (slice,rel), wave per node ------------
// t0s/t1s sliced [2][N][32]; partials p0s/p1s sliced [2][N][32].
__global__ __launch_bounds__(256) void
agg2_kernel(const unsigned short* __restrict__ t0s,
            const unsigned short* __restrict__ t1s,
            const int* __restrict__ csr, const int* __restrict__ off,
            unsigned short* __restrict__ p0s, unsigned short* __restrict__ p1s,
            int N, int twoE)
{
    const int combo = blockIdx.x & 3;
    const int slice = combo & 1;
    const int rel = combo >> 1;
    int node = (blockIdx.x >> 2) * 4 + (threadIdx.x >> 6);
    int lane = threadIdx.x & 63;
    if (node >= N) return;
    const int eg = lane >> 4;
    const int c2 = (lane & 15) * 2;
    const unsigned short* tb = (rel ? t1s : t0s) + (size_t)slice * N * 32;
    unsigned short* outp = (rel ? p1s : p0s) + (size_t)slice * N * 32;
    int w = rel * N + node;

    int o0 = off[w];
    int o1 = (w + 1 < 2 * N) ? off[w + 1] : twoE;
    int d = o1 - o0;

    float sx = 0.f, sy = 0.f;
    int j = o0;
    for (; j + 15 < o1; j += 16) {
        unsigned a[4];
#pragma unroll
        for (int q = 0; q < 4; ++q)
            a[q] = *(const unsigned*)(tb + (size_t)csr[j + q * 4 + eg] * 32 + c2);
#pragma unroll
        for (int q = 0; q < 4; ++q) { sx += bflo(a[q]); sy += bfhi(a[q]); }
    }
    for (; j < o1; j += 4) {
        int jj = j + eg;
        if (jj < o1) {
            unsigned a = *(const unsigned*)(tb + (size_t)csr[jj] * 32 + c2);
            sx += bflo(a); sy += bfhi(a);
        }
    }
    sx += __shfl_xor(sx, 16);
    sx += __shfl_xor(sx, 32);
    sy += __shfl_xor(sy, 16);
    sy += __shfl_xor(sy, 32);
    if (eg == 0) {
        float inv = 1.0f / fmaxf((float)d, 1.0f);
        *(unsigned*)(outp + (size_t)node * 32 + c2) = pack2(sx * inv, sy * inv);
    }
}

// ---- fuse2: h2s(sliced) = z2(row-major) + p0s + p1s ---------------------
__global__ __launch_bounds__(256) void
fuse2_kernel(const unsigned short* __restrict__ z2b,
             const unsigned short* __restrict__ p0s,
             const unsigned short* __restrict__ p1s,
             unsigned short* __restrict__ h2s, int N)
{
    int t = blockIdx.x * blockDim.x + threadIdx.x;
    if (t >= N * 32) return;
    int node = t >> 5;
    int cp = t & 31;
    int col = cp * 2;
    int slice = cp >> 4;
    int scol = col & 31;
    size_t so = ((size_t)slice * N + node) * 32 + scol;
    unsigned z = *(const unsigned*)(z2b + (size_t)node * 64 + col);
    unsigned a = *(const unsigned*)(p0s + so);
    unsigned b = *(const unsigned*)(p1s + so);
    float hx = bflo(z) + bflo(a) + bflo(b);
    float hy = bfhi(z) + bfhi(a) + bfhi(b);
    *(unsigned*)(h2s + so) = pack2(hx, hy);
}

// ---- score sliced: slice=blockIdx&1; partial dot + atomicAdd ------------
__global__ __launch_bounds__(256) void
score_all_kernel(const unsigned short* __restrict__ h2s, // [2][N][32] bf16
                 const int* __restrict__ psrc, const int* __restrict__ pdst,
                 const int* __restrict__ nsrc, const int* __restrict__ ndst,
                 float* __restrict__ out, int E, int En, int N)
{
    const int slice = blockIdx.x & 1;
    int t = (blockIdx.x >> 1) * 256 + threadIdx.x;
    int e = t >> 3;
    int c = t & 7;
    if (e >= E + En) return;
    int si, di;
    if (e < E) { si = psrc[e]; di = pdst[e]; }
    else       { si = nsrc[e - E]; di = ndst[e - E]; }
    const unsigned short* tb = h2s + (size_t)slice * N * 32;
    uint2 va = *(const uint2*)(tb + (size_t)si * 32 + c * 4);
    uint2 vb = *(const uint2*)(tb + (size_t)di * 32 + c * 4);
    float s = 0.0f;
    s = fmaf(bflo(va.x), bflo(vb.x), s);
    s = fmaf(bfhi(va.x), bfhi(vb.x), s);
    s = fmaf(bflo(va.y), bflo(vb.y), s);
    s = fmaf(bfhi(va.y), bfhi(vb.y), s);
    s += __shfl_xor(s, 1);
    s += __shfl_xor(s, 2);
    s += __shfl_xor(s, 4);
    if (c == 0) atomicAdd(&out[e], s);
}

extern "C" void kernel_launch(void* const* d_in, const int* in_sizes, int n_in,
                              void* d_out, int out_size, void* d_ws, size_t ws_size,
                              hipStream_t stream)
{
    const float* x     = (const float*)d_in[0];
    const int*   edges = (const int*)d_in[1];
    const int*   neg   = (const int*)d_in[2];
    const float* Wn1   = (const float*)d_in[3];
    const float* Ws1   = (const float*)d_in[4];
    const float* b1    = (const float*)d_in[5];
    const float* Wn2   = (const float*)d_in[6];
    const float* Ws2   = (const float*)d_in[7];
    const float* b2    = (const float*)d_in[8];
    float* out = (float*)d_out;

    const int Fin = 128, R = 2;
    const int N  = in_sizes[0] / Fin;        // 50000
    const int E  = in_sizes[1] / (R * 2);    // 800000
    const int En = in_sizes[2] / 2;          // 800000
    const int twoE = 2 * E;
    const int NBK = (N + BW - 1) / BW;       // 391
    const int rbT = 2 * NBK;

    // ---- workspace layout ----
    unsigned short* xs   = (unsigned short*)d_ws;      // [4][N][32] bf16 (p0s/p1s reuse)
    unsigned short* h1b  = xs + (size_t)N * 128;       // [N,128] bf16
    unsigned short* m0s  = h1b + (size_t)N * 128;      // [4][N][32] bf16
    unsigned short* m1s  = m0s + (size_t)N * 128;      // [4][N][32] bf16
    unsigned* staging = (unsigned*)(m1s + (size_t)N * 128); // [2E] packed
    unsigned short* WT1z = (unsigned short*)(staging + (size_t)twoE); // [128,128]
    unsigned short* WT1a = WT1z + 16384;
    unsigned short* WT1b = WT1a + 16384;
    unsigned short* WT2z = WT1b + 16384;               // [64,128]
    unsigned short* WT2a = WT2z + 8192;
    unsigned short* WT2b = WT2a + 8192;
    float* bc1 = (float*)(WT2b + 8192);                // [128]
    float* bc2 = bc1 + 128;                            // [64]
    int* bcnt = (int*)(bc2 + 64);                      // [2*NBK_MAX]
    int* gcur = bcnt + 2 * NBK_MAX;                    // [2*NBK_MAX]
    int* bko  = gcur + 2 * NBK_MAX;                    // [2*NBK_MAX+1]
    int* off  = bko + 2 * NBK_MAX + 1;                 // [2N]
    int* csr  = off + (size_t)2 * N;                   // [2E]

    // layer-2 aliases (m0s/m1s dead after gemm3; xs dead after gemm3)
    unsigned short* z2b = m0s;                         // [N,64] row-major
    unsigned short* t0s = m0s + (size_t)N * 64;        // [2][N][32]
    unsigned short* t1s = m1s;                         // [2][N][32]
    unsigned short* h2s = m1s + (size_t)N * 64;        // [2][N][32]
    unsigned short* p0s = xs;                          // [2][N][32]
    unsigned short* p1s = xs + (size_t)N * 64;         // [2][N][32]

    const int BS = 256;
    const int edge_blocks = (twoE + EPB - 1) / EPB;
    const int gx = (N + 63) / 64;

    // ---- CSR build (radix by dst bucket, packed staging) ----
    hipMemsetAsync(bcnt, 0, (size_t)4 * NBK_MAX * sizeof(int), stream);
    bucket_count_kernel<<<edge_blocks, BS, 0, stream>>>(edges, bcnt, NBK, E);
    bucket_scan_kernel<<<1, 1024, 0, stream>>>(bcnt, bko, rbT, twoE);
    partition_kernel<<<edge_blocks, BS, 0, stream>>>(edges, bko, gcur, staging, NBK, E);
    bucket_csr_kernel<<<rbT, BS, 0, stream>>>(staging, bko, csr, off, NBK, N);

    // ---- prep ----
    cvt_sliced_kernel<<<(N * 16 + BS - 1) / BS, BS, 0, stream>>>(x, xs, N);
    prep_kernel<<<(16384 + BS - 1) / BS, BS, 0, stream>>>(
        Ws1, Wn1, b1, Ws2, Wn2, b2,
        WT1z, WT1a, WT1b, bc1, WT2z, WT2a, WT2b, bc2);

    // ---- Layer 1: sliced aggregate-first, fused MFMA GEMM ----
    agg1x_kernel<<<4 * ((2 * N + 3) / 4), BS, 0, stream>>>(xs, csr, off, m0s, m1s, N, twoE);
    gemm3_mfma_kernel<<<gx, BS, 0, stream>>>(xs, m0s, m1s, WT1z, WT1a, WT1b, bc1, h1b, N);

    // ---- Layer 2: transform-first, sliced tables, partials + fuse ----
    gemm2_mfma_kernel<<<gx, BS, 0, stream>>>(h1b, WT2z, WT2a, WT2b, bc2, z2b, t0s, t1s, N);
    agg2_kernel<<<4 * ((N + 3) / 4), BS, 0, stream>>>(t0s, t1s, csr, off, p0s, p1s, N, twoE);
    fuse2_kernel<<<(N * 32 + BS - 1) / BS, BS, 0, stream>>>(z2b, p0s, p1s, h2s, N);

    // ---- Scores (sliced partial dots, atomic accumulate) ----
    hipMemsetAsync(out, 0, (size_t)(E + En) * sizeof(float), stream);
    score_all_kernel<<<2 * (((E + En) * 8 + BS - 1) / BS), BS, 0, stream>>>(
        h2s, edges, edges + E, neg, neg + En, out, E, En, N);
}

// Round 12
// 393.071 us; speedup vs baseline: 1.2478x; 1.2478x over previous
//
#include <hip/hip_runtime.h>

// ---------------------------------------------------------------------------
// GraphSAGE 2-layer hetero (R=2) + edge dot scorer.  Round 12:
//  * Revert round-11 slicing (it traded HBM-miss bound for a 4x VALU/index
//    bound: FETCH 150->39 MB but 65->130 us). Round-10 full-row gathers.
//  * agg kernels at 512 threads/block: 8 waves x 4 blocks = 32 waves/CU
//    (round-10 occupancy capped at ~66% by workgroup slots, VGPR=32).
//  * agg2 single kernel (both relations + z2 + h2 write); fuse2 deleted.
//  * CSR build: pass A records per-block bucket bases via atomicAdd return;
//    partition drops its counting loop (one fewer edges pass).
//  * cvt + weight-prep merged into one launch.
// ---------------------------------------------------------------------------

#define BW 128            // nodes per radix bucket (pow2)
#define NBK_MAX 1024
#define EPB 8192          // edges per block in radix passes

typedef __attribute__((ext_vector_type(8))) short bf16x8;
typedef __attribute__((ext_vector_type(4))) float floatx4;

__device__ __forceinline__ unsigned short f2bf(float f) {
    unsigned u = __float_as_uint(f);
    unsigned r = u + 0x7FFFu + ((u >> 16) & 1u);
    return (unsigned short)(r >> 16);
}
__device__ __forceinline__ unsigned pack2(float a, float b) {
    return (unsigned)f2bf(a) | ((unsigned)f2bf(b) << 16);
}
__device__ __forceinline__ float bflo(unsigned v) { return __uint_as_float(v << 16); }
__device__ __forceinline__ float bfhi(unsigned v) { return __uint_as_float(v & 0xFFFF0000u); }

// ---- radix pass A: per-(r,bucket) counts + per-block bases ---------------
__global__ __launch_bounds__(256) void
bucket_count_kernel(const int* __restrict__ edges, int* __restrict__ bcnt,
                    int* __restrict__ pbase, int NBK, int E)
{
    __shared__ int cnt[2 * NBK_MAX];
    const int rbT = 2 * NBK;
    const int t = threadIdx.x;
    for (int k = t; k < rbT; k += 256) cnt[k] = 0;
    __syncthreads();
    long long start = (long long)blockIdx.x * EPB;
    long long twoE = 2LL * E;
    for (int u = 0; u < EPB / 256; ++u) {
        long long idx = start + u * 256 + t;
        if (idx < twoE) {
            int r = idx >= E;
            int e = (int)(idx - (long long)r * E);
            int d = edges[(size_t)r * 2 * E + E + e];
            atomicAdd(&cnt[r * NBK + (d >> 7)], 1);
        }
    }
    __syncthreads();
    for (int k = t; k < rbT; k += 256)
        if (cnt[k])
            pbase[(size_t)blockIdx.x * rbT + k] = atomicAdd(&bcnt[k], cnt[k]);
}

// ---- radix pass B: exclusive scan of bucket counts ----------------------
__global__ __launch_bounds__(1024) void
bucket_scan_kernel(const int* __restrict__ bcnt, int* __restrict__ bko,
                   int rbT, int twoE)
{
    __shared__ int sm[1024];
    int t = threadIdx.x;
    int v = (t < rbT) ? bcnt[t] : 0;
    sm[t] = v;
    __syncthreads();
    for (int s = 1; s < 1024; s <<= 1) {
        int u = (t >= s) ? sm[t - s] : 0;
        __syncthreads();
        sm[t] += u;
        __syncthreads();
    }
    if (t < rbT) bko[t] = sm[t] - v;
    if (t == 0) bko[rbT] = twoE;
}

// ---- radix pass C: partition using recorded bases (no recount) ----------
__global__ __launch_bounds__(256) void
partition_kernel(const int* __restrict__ edges, const int* __restrict__ bko,
                 const int* __restrict__ pbase, unsigned* __restrict__ staging,
                 int NBK, int E)
{
    __shared__ int cnt[2 * NBK_MAX];
    __shared__ int base[2 * NBK_MAX];
    const int rbT = 2 * NBK;
    const int t = threadIdx.x;
    for (int k = t; k < rbT; k += 256) {
        cnt[k] = 0;
        base[k] = bko[k] + pbase[(size_t)blockIdx.x * rbT + k];
    }
    __syncthreads();
    long long start = (long long)blockIdx.x * EPB;
    long long twoE = 2LL * E;
    for (int u = 0; u < EPB / 256; ++u) {
        long long idx = start + u * 256 + t;
        if (idx < twoE) {
            int r = idx >= E;
            int e = (int)(idx - (long long)r * E);
            int s = edges[(size_t)r * 2 * E + e];
            int d = edges[(size_t)r * 2 * E + E + e];
            int rb = r * NBK + (d >> 7);
            int pos = atomicAdd(&cnt[rb], 1);
            staging[(size_t)base[rb] + pos] = (unsigned)s | ((unsigned)(d & 127) << 24);
        }
    }
}

// ---- radix pass D: per-bucket node hist/scan -> off[] and csr[] ----------
__global__ __launch_bounds__(256) void
bucket_csr_kernel(const unsigned* __restrict__ staging, const int* __restrict__ bko,
                  int* __restrict__ csr, int* __restrict__ off,
                  int NBK, int N)
{
    __shared__ int hist[BW], excl[BW], cur[BW], sc[BW];
    const int rb = blockIdx.x;
    const int r = rb / NBK;
    const int b = rb % NBK;
    const int node0 = b * BW;
    const int nn = min(BW, N - node0);
    const int cbase = bko[rb];
    const int c = bko[rb + 1] - cbase;
    const int t = threadIdx.x;

    if (t < BW) { hist[t] = 0; cur[t] = 0; }
    __syncthreads();
    for (int k = t; k < c; k += 256)
        atomicAdd(&hist[staging[(size_t)cbase + k] >> 24], 1);
    __syncthreads();
    if (t < BW) sc[t] = hist[t];
    __syncthreads();
    for (int s = 1; s < BW; s <<= 1) {
        int v = (t < BW && t >= s) ? sc[t - s] : 0;
        __syncthreads();
        if (t < BW) sc[t] += v;
        __syncthreads();
    }
    if (t < BW) excl[t] = sc[t] - hist[t];
    if (t < nn) off[(size_t)r * N + node0 + t] = cbase + excl[t];
    __syncthreads();
    for (int k = t; k < c; k += 256) {
        unsigned pr = staging[(size_t)cbase + k];
        int l = (int)(pr >> 24);
        int pos = atomicAdd(&cur[l], 1);
        csr[(size_t)cbase + excl[l] + pos] = (int)(pr & 0xFFFFFFu);
    }
}

// ---- merged cvt (x->bf16) + weight prep ---------------------------------
__global__ __launch_bounds__(256) void
prep_all_kernel(const float* __restrict__ x, unsigned short* __restrict__ xb, int n4,
                const float* __restrict__ Ws1, const float* __restrict__ Wn1,
                const float* __restrict__ b1,
                const float* __restrict__ Ws2, const float* __restrict__ Wn2,
                const float* __restrict__ b2,
                unsigned short* __restrict__ WT1z, unsigned short* __restrict__ WT1a,
                unsigned short* __restrict__ WT1b, float* __restrict__ bc1,
                unsigned short* __restrict__ WT2z, unsigned short* __restrict__ WT2a,
                unsigned short* __restrict__ WT2b, float* __restrict__ bc2)
{
    int t = blockIdx.x * blockDim.x + threadIdx.x;
    if (t < n4) {
        float4 v = ((const float4*)x)[t];
        ushort4 r;
        r.x = f2bf(v.x); r.y = f2bf(v.y); r.z = f2bf(v.z); r.w = f2bf(v.w);
        ((ushort4*)xb)[t] = r;
    }
    if (t < 16384) {                 // layer 1 W^T: [n][k] <- [k][n]
        int n = t >> 7, k = t & 127;
        int in = k * 128 + n;
        WT1z[t] = f2bf(Ws1[in] + Ws1[16384 + in]);
        WT1a[t] = f2bf(Wn1[in]);
        WT1b[t] = f2bf(Wn1[16384 + in]);
    }
    if (t < 8192) {                  // layer 2: n < 64, k < 128
        int n = t >> 7, k = t & 127;
        int in = k * 64 + n;
        WT2z[t] = f2bf(Ws2[in] + Ws2[8192 + in]);
        WT2a[t] = f2bf(Wn2[in]);
        WT2b[t] = f2bf(Wn2[8192 + in]);
    }
    if (t < 128) bc1[t] = b1[t] + b1[128 + t];
    if (t < 64)  bc2[t] = b2[t] + b2[64 + t];
}

// ---- agg1x: wave per (relation,node), full 128-col rows, unroll x16 ------
__global__ __launch_bounds__(512) void
agg1x_kernel(const unsigned short* __restrict__ xb,
             const int* __restrict__ csr, const int* __restrict__ off,
             unsigned short* __restrict__ m0, unsigned short* __restrict__ m1,
             int N, int twoE)
{
    int w = blockIdx.x * 8 + (threadIdx.x >> 6);
    int lane = threadIdx.x & 63;
    if (w >= 2 * N) return;
    const int col = lane * 2;
    unsigned short* outp = (w < N) ? m0 : m1;
    int node = (w < N) ? w : w - N;

    int o0 = off[w];
    int o1 = (w + 1 < 2 * N) ? off[w + 1] : twoE;
    int d = o1 - o0;

    float sx = 0.f, sy = 0.f;
    int j = o0;
    for (; j + 15 < o1; j += 16) {
        unsigned a[16];
#pragma unroll
        for (int q = 0; q < 16; ++q)
            a[q] = *(const unsigned*)(xb + (size_t)csr[j + q] * 128 + col);
#pragma unroll
        for (int q = 0; q < 16; ++q) { sx += bflo(a[q]); sy += bfhi(a[q]); }
    }
    for (; j + 3 < o1; j += 4) {
        unsigned a0 = *(const unsigned*)(xb + (size_t)csr[j] * 128 + col);
        unsigned a1 = *(const unsigned*)(xb + (size_t)csr[j + 1] * 128 + col);
        unsigned a2 = *(const unsigned*)(xb + (size_t)csr[j + 2] * 128 + col);
        unsigned a3 = *(const unsigned*)(xb + (size_t)csr[j + 3] * 128 + col);
        sx += (bflo(a0) + bflo(a1)) + (bflo(a2) + bflo(a3));
        sy += (bfhi(a0) + bfhi(a1)) + (bfhi(a2) + bfhi(a3));
    }
    for (; j < o1; ++j) {
        unsigned a = *(const unsigned*)(xb + (size_t)csr[j] * 128 + col);
        sx += bflo(a); sy += bfhi(a);
    }
    float inv = 1.0f / fmaxf((float)d, 1.0f);
    *(unsigned*)(outp + (size_t)node * 128 + col) = pack2(sx * inv, sy * inv);
}

// ---- gemm3 (layer 1): h1 = relu(xb@W0 + m0@W1 + m1@W2 + bias) -> bf16 ---
__global__ __launch_bounds__(256) void
gemm3_mfma_kernel(const unsigned short* __restrict__ xb,
                  const unsigned short* __restrict__ m0,
                  const unsigned short* __restrict__ m1,
                  const unsigned short* __restrict__ WT0,
                  const unsigned short* __restrict__ WT1,
                  const unsigned short* __restrict__ WT2,
                  const float* __restrict__ bias,
                  unsigned short* __restrict__ h1b, int N)
{
    __shared__ float eb[64][129];
    const int tid = threadIdx.x;
    const int wave = tid >> 6;
    const int lane = tid & 63;
    const int m = lane & 15;
    const int quad = lane >> 4;

    floatx4 acc[8];
    const floatx4 z4 = {0.f, 0.f, 0.f, 0.f};
#pragma unroll
    for (int t = 0; t < 8; ++t) acc[t] = z4;

    int arow = blockIdx.x * 64 + wave * 16 + m;
    if (arow >= N) arow = N - 1;

    const unsigned short* Asrc[3] = {xb, m0, m1};
    const unsigned short* Bsrc[3] = {WT0, WT1, WT2};
#pragma unroll
    for (int s3 = 0; s3 < 3; ++s3) {
        const unsigned short* ap = Asrc[s3] + (size_t)arow * 128 + quad * 8;
        const unsigned short* bp = Bsrc[s3];
#pragma unroll
        for (int s = 0; s < 4; ++s) {
            bf16x8 a = *(const bf16x8*)(ap + s * 32);
#pragma unroll
            for (int t = 0; t < 8; ++t) {
                bf16x8 b = *(const bf16x8*)(bp + (size_t)(t * 16 + m) * 128 + s * 32 + quad * 8);
                acc[t] = __builtin_amdgcn_mfma_f32_16x16x32_bf16(a, b, acc[t], 0, 0, 0);
            }
        }
    }

#pragma unroll
    for (int t = 0; t < 8; ++t)
#pragma unroll
        for (int i = 0; i < 4; ++i)
            eb[wave * 16 + quad * 4 + i][t * 16 + m] = acc[t][i];
    __syncthreads();

#pragma unroll
    for (int j = 0; j < 4; ++j) {
        int lr = wave * 16 + j * 4 + quad;
        int grow = blockIdx.x * 64 + lr;
        if (grow < N) {
#pragma unroll
            for (int i = 0; i < 2; ++i) {
                int c0 = (i * 16 + m) * 4;
                float v0 = fmaxf(eb[lr][c0 + 0] + bias[c0 + 0], 0.0f);
                float v1 = fmaxf(eb[lr][c0 + 1] + bias[c0 + 1], 0.0f);
                float v2 = fmaxf(eb[lr][c0 + 2] + bias[c0 + 2], 0.0f);
                float v3 = fmaxf(eb[lr][c0 + 3] + bias[c0 + 3], 0.0f);
                ushort4 u;
                u.x = f2bf(v0); u.y = f2bf(v1); u.z = f2bf(v2); u.w = f2bf(v3);
                *(ushort4*)(h1b + (size_t)grow * 128 + c0) = u;
            }
        }
    }
}

// ---- gemm2 (layer 2): one A pass -> z2b(bf16,+bias), t0, t1 [N,64] ------
__global__ __launch_bounds__(256) void
gemm2_mfma_kernel(const unsigned short* __restrict__ h1b,
                  const unsigned short* __restrict__ WTz,
                  const unsigned short* __restrict__ WTa,
                  const unsigned short* __restrict__ WTb,
                  const float* __restrict__ bias,
                  unsigned short* __restrict__ z2b,
                  unsigned short* __restrict__ t0, unsigned short* __restrict__ t1,
                  int N)
{
    __shared__ float eb[64][65];
    const int tid = threadIdx.x;
    const int wave = tid >> 6;
    const int lane = tid & 63;
    const int m = lane & 15;
    const int quad = lane >> 4;

    floatx4 acc[3][4];
    const floatx4 z4 = {0.f, 0.f, 0.f, 0.f};
#pragma unroll
    for (int o = 0; o < 3; ++o)
#pragma unroll
        for (int t = 0; t < 4; ++t) acc[o][t] = z4;

    int arow = blockIdx.x * 64 + wave * 16 + m;
    if (arow >= N) arow = N - 1;
    const unsigned short* ap = h1b + (size_t)arow * 128 + quad * 8;
    const unsigned short* Bsrc[3] = {WTz, WTa, WTb};

#pragma unroll
    for (int s = 0; s < 4; ++s) {
        bf16x8 a = *(const bf16x8*)(ap + s * 32);
#pragma unroll
        for (int o = 0; o < 3; ++o)
#pragma unroll
            for (int t = 0; t < 4; ++t) {
                bf16x8 b = *(const bf16x8*)(Bsrc[o] + (size_t)(t * 16 + m) * 128 + s * 32 + quad * 8);
                acc[o][t] = __builtin_amdgcn_mfma_f32_16x16x32_bf16(a, b, acc[o][t], 0, 0, 0);
            }
    }

    unsigned short* Od[3] = {z2b, t0, t1};
#pragma unroll
    for (int o = 0; o < 3; ++o) {
#pragma unroll
        for (int t = 0; t < 4; ++t)
#pragma unroll
            for (int i = 0; i < 4; ++i)
                eb[wave * 16 + quad * 4 + i][t * 16 + m] = acc[o][t][i];
        __syncthreads();
#pragma unroll
        for (int j = 0; j < 4; ++j) {
            int lr = wave * 16 + j * 4 + quad;
            int grow = blockIdx.x * 64 + lr;
            if (grow < N) {
                int c0 = m * 4;
                float v0 = eb[lr][c0 + 0], v1 = eb[lr][c0 + 1];
                float v2 = eb[lr][c0 + 2], v3 = eb[lr][c0 + 3];
                if (o == 0) {
                    v0 += bias[c0 + 0]; v1 += bias[c0 + 1];
                    v2 += bias[c0 + 2]; v3 += bias[c0 + 3];
                }
                ushort4 u;
                u.x = f2bf(v0); u.y = f2bf(v1); u.z = f2bf(v2); u.w = f2bf(v3);
                *(ushort4*)(Od[o] + (size_t)grow * 64 + c0) = u;
            }
        }
        __syncthreads();
    }
}

// ---- agg2: wave per node, both relations, 64 cols, unroll x8/half --------
__global__ __launch_bounds__(512) void
agg2_kernel(const unsigned short* __restrict__ t0,
            const unsigned short* __restrict__ t1,
            const unsigned short* __restrict__ z2b,
            const int* __restrict__ csr, const int* __restrict__ off,
            unsigned short* __restrict__ h2b, int N, int twoE)
{
    int w = blockIdx.x * 8 + (threadIdx.x >> 6);
    int lane = threadIdx.x & 63;
    if (w >= N) return;
    const int half = lane >> 5;
    const int col = (lane & 31) * 2;

    float sx0 = 0.f, sy0 = 0.f, sx1 = 0.f, sy1 = 0.f;
    int o0 = off[w], o1 = off[w + 1];
    int d0 = o1 - o0;
    int j = o0 + half;
    for (; j + 14 < o1; j += 16) {
        unsigned a[8];
#pragma unroll
        for (int q = 0; q < 8; ++q)
            a[q] = *(const unsigned*)(t0 + (size_t)csr[j + 2 * q] * 64 + col);
#pragma unroll
        for (int q = 0; q < 8; ++q) { sx0 += bflo(a[q]); sy0 += bfhi(a[q]); }
    }
    for (; j < o1; j += 2) {
        unsigned a = *(const unsigned*)(t0 + (size_t)csr[j] * 64 + col);
        sx0 += bflo(a); sy0 += bfhi(a);
    }
    int p = N + w;
    o0 = off[p];
    o1 = (p + 1 < 2 * N) ? off[p + 1] : twoE;
    int d1 = o1 - o0;
    j = o0 + half;
    for (; j + 14 < o1; j += 16) {
        unsigned a[8];
#pragma unroll
        for (int q = 0; q < 8; ++q)
            a[q] = *(const unsigned*)(t1 + (size_t)csr[j + 2 * q] * 64 + col);
#pragma unroll
        for (int q = 0; q < 8; ++q) { sx1 += bflo(a[q]); sy1 += bfhi(a[q]); }
    }
    for (; j < o1; j += 2) {
        unsigned a = *(const unsigned*)(t1 + (size_t)csr[j] * 64 + col);
        sx1 += bflo(a); sy1 += bfhi(a);
    }
    sx0 += __shfl_xor(sx0, 32);
    sy0 += __shfl_xor(sy0, 32);
    sx1 += __shfl_xor(sx1, 32);
    sy1 += __shfl_xor(sy1, 32);
    if (half == 0) {
        float inv0 = 1.0f / fmaxf((float)d0, 1.0f);
        float inv1 = 1.0f / fmaxf((float)d1, 1.0f);
        unsigned zz = *(const unsigned*)(z2b + (size_t)w * 64 + col);
        float hx = bflo(zz) + sx0 * inv0 + sx1 * inv1;
        float hy = bfhi(zz) + sy0 * inv0 + sy1 * inv1;
        *(unsigned*)(h2b + (size_t)w * 64 + col) = pack2(hx, hy);
    }
}

// ---- merged score: pos then neg; 8 lanes/edge ---------------------------
__global__ __launch_bounds__(256) void
score_all_kernel(const unsigned short* __restrict__ h, // [N,64] bf16
                 const int* __restrict__ psrc, const int* __restrict__ pdst,
                 const int* __restrict__ nsrc, const int* __restrict__ ndst,
                 float* __restrict__ out, int E, int En)
{
    int t = blockIdx.x * blockDim.x + threadIdx.x;
    int e = t >> 3;
    int c = t & 7;
    if (e >= E + En) return;
    int si, di;
    if (e < E) { si = psrc[e]; di = pdst[e]; }
    else       { si = nsrc[e - E]; di = ndst[e - E]; }
    uint4 va = *(const uint4*)(h + (size_t)si * 64 + c * 8);
    uint4 vb = *(const uint4*)(h + (size_t)di * 64 + c * 8);
    float s = 0.0f;
    s = fmaf(bflo(va.x), bflo(vb.x), s);
    s = fmaf(bfhi(va.x), bfhi(vb.x), s);
    s = fmaf(bflo(va.y), bflo(vb.y), s);
    s = fmaf(bfhi(va.y), bfhi(vb.y), s);
    s = fmaf(bflo(va.z), bflo(vb.z), s);
    s = fmaf(bfhi(va.z), bfhi(vb.z), s);
    s = fmaf(bflo(va.w), bflo(vb.w), s);
    s = fmaf(bfhi(va.w), bfhi(vb.w), s);
    s += __shfl_xor(s, 1);
    s += __shfl_xor(s, 2);
    s += __shfl_xor(s, 4);
    if (c == 0) out[e] = s;
}

extern "C" void kernel_launch(void* const* d_in, const int* in_sizes, int n_in,
                              void* d_out, int out_size, void* d_ws, size_t ws_size,
                              hipStream_t stream)
{
    const float* x     = (const float*)d_in[0];
    const int*   edges = (const int*)d_in[1];
    const int*   neg   = (const int*)d_in[2];
    const float* Wn1   = (const float*)d_in[3];
    const float* Ws1   = (const float*)d_in[4];
    const float* b1    = (const float*)d_in[5];
    const float* Wn2   = (const float*)d_in[6];
    const float* Ws2   = (const float*)d_in[7];
    const float* b2    = (const float*)d_in[8];
    float* out = (float*)d_out;

    const int Fin = 128, R = 2;
    const int N  = in_sizes[0] / Fin;        // 50000
    const int E  = in_sizes[1] / (R * 2);    // 800000
    const int En = in_sizes[2] / 2;          // 800000
    const int twoE = 2 * E;
    const int NBK = (N + BW - 1) / BW;       // 391
    const int rbT = 2 * NBK;
    const int edge_blocks = (twoE + EPB - 1) / EPB;

    // ---- workspace layout ----
    unsigned short* xb  = (unsigned short*)d_ws;       // [N,128] bf16
    unsigned short* h1b = xb + (size_t)N * 128;        // [N,128] bf16
    unsigned short* m0  = h1b + (size_t)N * 128;       // [N,128] bf16
    unsigned short* m1  = m0 + (size_t)N * 128;        // [N,128] bf16
    unsigned* staging = (unsigned*)(m1 + (size_t)N * 128); // [2E] packed
    unsigned short* WT1z = (unsigned short*)(staging + (size_t)twoE); // [128,128]
    unsigned short* WT1a = WT1z + 16384;
    unsigned short* WT1b = WT1a + 16384;
    unsigned short* WT2z = WT1b + 16384;               // [64,128]
    unsigned short* WT2a = WT2z + 8192;
    unsigned short* WT2b = WT2a + 8192;
    float* bc1 = (float*)(WT2b + 8192);                // [128]
    float* bc2 = bc1 + 128;                            // [64]
    int* bcnt = (int*)(bc2 + 64);                      // [2*NBK_MAX]
    int* bko  = bcnt + 2 * NBK_MAX;                    // [2*NBK_MAX+1]
    int* off  = bko + 2 * NBK_MAX + 1;                 // [2N]
    int* csr  = off + (size_t)2 * N;                   // [2E]
    int* pbase = csr + (size_t)twoE;                   // [edge_blocks * rbT]

    // layer-2 aliases (m0/m1 dead after gemm3)
    unsigned short* z2b = m0;                          // [N,64]
    unsigned short* t0  = m0 + (size_t)N * 64;         // [N,64]
    unsigned short* t1  = m1;                          // [N,64]
    unsigned short* h2b = m1 + (size_t)N * 64;         // [N,64]

    const int BS = 256;
    const int gx = (N + 63) / 64;

    // ---- CSR build (radix by dst bucket, recorded bases) ----
    hipMemsetAsync(bcnt, 0, (size_t)2 * NBK_MAX * sizeof(int), stream);
    bucket_count_kernel<<<edge_blocks, BS, 0, stream>>>(edges, bcnt, pbase, NBK, E);
    bucket_scan_kernel<<<1, 1024, 0, stream>>>(bcnt, bko, rbT, twoE);
    partition_kernel<<<edge_blocks, BS, 0, stream>>>(edges, bko, pbase, staging, NBK, E);
    bucket_csr_kernel<<<rbT, BS, 0, stream>>>(staging, bko, csr, off, NBK, N);

    // ---- prep (cvt + weights merged) ----
    {
        int n4 = N * 32;
        prep_all_kernel<<<(n4 + BS - 1) / BS, BS, 0, stream>>>(
            x, xb, n4, Ws1, Wn1, b1, Ws2, Wn2, b2,
            WT1z, WT1a, WT1b, bc1, WT2z, WT2a, WT2b, bc2);
    }

    // ---- Layer 1: aggregate-first, fused MFMA GEMM ----
    agg1x_kernel<<<(2 * N + 7) / 8, 512, 0, stream>>>(xb, csr, off, m0, m1, N, twoE);
    gemm3_mfma_kernel<<<gx, BS, 0, stream>>>(xb, m0, m1, WT1z, WT1a, WT1b, bc1, h1b, N);

    // ---- Layer 2: transform-first, single agg kernel ----
    gemm2_mfma_kernel<<<gx, BS, 0, stream>>>(h1b, WT2z, WT2a, WT2b, bc2, z2b, t0, t1, N);
    agg2_kernel<<<(N + 7) / 8, 512, 0, stream>>>(t0, t1, z2b, csr, off, h2b, N, twoE);

    // ---- Scores (merged) ----
    score_all_kernel<<<((E + En) * 8 + BS - 1) / BS, BS, 0, stream>>>(
        h2b, edges, edges + E, neg, neg + En, out, E, En);
}